// Round 1
// baseline (479.953 us; speedup 1.0000x reference)
//
#include <hip/hip_runtime.h>
#include <math.h>

#define NCLS 3

// ---------------------------------------------------------------------------
// Pass 1: nll_neg[b,a,s] = -log_softmax(logit)[b, class=0, a, s]
// logit layout: (B, NCLS*A, S) with channel = n*A + a
// ---------------------------------------------------------------------------
__global__ void nll_neg_kernel(const float* __restrict__ logit,
                               float* __restrict__ nll_neg,
                               int B, int A, int S) {
    int total = B * A * S;
    int stride = gridDim.x * blockDim.x;
    for (int idx = blockIdx.x * blockDim.x + threadIdx.x; idx < total; idx += stride) {
        int s = idx % S;
        int ba = idx / S;
        int a = ba % A;
        int b = ba / A;
        const float* p = logit + ((long)b * NCLS * A + a) * S + s;
        float l0 = p[0];
        float l1 = p[(long)A * S];
        float l2 = p[2L * A * S];
        float m = fmaxf(l0, fmaxf(l1, l2));
        float e0 = __expf(l0 - m);
        float e1 = __expf(l1 - m);
        float e2 = __expf(l2 - m);
        float lsum = __logf(e0 + e1 + e2);
        // nll_neg = -((l0 - m) - lsum)
        nll_neg[idx] = lsum - (l0 - m);
    }
}

// ---------------------------------------------------------------------------
// Pass 2: negative focal loss with 3x3x3 NMS on the stored nll_neg map.
// Bit-exact tie rule: keep position iff it equals the neighborhood max.
// Accumulate into out[1] (loss_neg) and out[3] (count_neg).
// ---------------------------------------------------------------------------
__global__ void neg_loss_kernel(const float* __restrict__ nll,
                                const float* __restrict__ prob_gt,
                                float* __restrict__ out,
                                int B, int A, int D, int H, int W) {
    int S = D * H * W;
    int total = B * A * S;
    int stride = gridDim.x * blockDim.x;
    float loss = 0.f, cnt = 0.f;
    for (int idx = blockIdx.x * blockDim.x + threadIdx.x; idx < total; idx += stride) {
        float c = nll[idx];
        if (prob_gt[idx] == -1.0f) {
            int w = idx % W;
            int t = idx / W;
            int h = t % H; t /= H;
            int d = t % D;
            int ba = t / D;
            const float* basep = nll + (long)ba * S;
            float mp = c;
            int d0 = max(d - 1, 0), d1 = min(d + 1, D - 1);
            int h0 = max(h - 1, 0), h1 = min(h + 1, H - 1);
            int w0 = max(w - 1, 0), w1 = min(w + 1, W - 1);
            for (int dd = d0; dd <= d1; ++dd)
                for (int hh = h0; hh <= h1; ++hh)
                    for (int ww = w0; ww <= w1; ++ww)
                        mp = fmaxf(mp, basep[(dd * H + hh) * W + ww]);
            if (mp == c) {
                float pn = __expf(-c);
                float wn = (1.f - pn) * (1.f - pn);
                loss += c * wn;
                cnt += wn;
            }
        }
    }
    // wave (64-lane) reduce, then cross-wave via LDS, one atomic pair per block
    for (int off = 32; off > 0; off >>= 1) {
        loss += __shfl_down(loss, off);
        cnt  += __shfl_down(cnt, off);
    }
    __shared__ float sl[8], sc[8];
    int wave = threadIdx.x >> 6;
    int lane = threadIdx.x & 63;
    if (lane == 0) { sl[wave] = loss; sc[wave] = cnt; }
    __syncthreads();
    if (threadIdx.x == 0) {
        int nw = blockDim.x >> 6;
        float L = 0.f, C = 0.f;
        for (int i = 0; i < nw; ++i) { L += sl[i]; C += sc[i]; }
        atomicAdd(&out[1], L);
        atomicAdd(&out[3], C);
    }
}

// ---------------------------------------------------------------------------
// Pass 3: positive gathers. out[0] += nll_t*w_pos, out[2] += w_pos.
// ---------------------------------------------------------------------------
__global__ void pos_loss_kernel(const float* __restrict__ logit,
                                const float* __restrict__ prob_gt,
                                const int* __restrict__ coord,
                                const float* __restrict__ wcls,
                                float* __restrict__ out,
                                int B, int A, int D, int H, int W, int P) {
    int i = blockIdx.x * blockDim.x + threadIdx.x;
    if (i >= B * P) return;
    int b = i / P;
    const int* c = coord + (long)i * 4;
    int a = c[0];
    float loss = 0.f, cnt = 0.f;
    if (a > -1) {
        int d = c[1], h = c[2], w = c[3];
        int S = D * H * W;
        int s = (d * H + h) * W + w;
        int cls = (int)prob_gt[((long)b * A + a) * S + s];
        const float* lp = logit + ((long)b * NCLS * A + a) * S + s;
        float l0 = lp[0];
        float l1 = lp[(long)A * S];
        float l2 = lp[2L * A * S];
        float m = fmaxf(l0, fmaxf(l1, l2));
        float e0 = __expf(l0 - m);
        float e1 = __expf(l1 - m);
        float e2 = __expf(l2 - m);
        float lsum = __logf(e0 + e1 + e2);
        float lc = (cls == 0) ? l0 : ((cls == 1) ? l1 : l2);
        float lpc = (lc - m) - lsum;
        float pt = __expf(lpc);
        float wp = (1.f - pt) * (1.f - pt) * wcls[cls];
        loss = (-lpc) * wp;
        cnt = wp;
    }
    atomicAdd(&out[0], loss);
    atomicAdd(&out[2], cnt);
}

extern "C" void kernel_launch(void* const* d_in, const int* in_sizes, int n_in,
                              void* d_out, int out_size, void* d_ws, size_t ws_size,
                              hipStream_t stream) {
    const float* logit0   = (const float*)d_in[0];
    const float* logit1   = (const float*)d_in[1];
    const float* prob_gt0 = (const float*)d_in[2];
    const float* prob_gt1 = (const float*)d_in[3];
    const int*   coord0   = (const int*)d_in[4];
    const int*   coord1   = (const int*)d_in[5];
    const float* wcls     = (const float*)d_in[6];
    float* out = (float*)d_out;

    const int B = 4, A = 3, P = 128;
    const int D0 = 64, H0 = 64, W0 = 64, S0 = D0 * H0 * W0;
    const int D1 = 32, H1 = 32, W1 = 32, S1 = D1 * H1 * W1;
    const int n0 = B * A * S0;   // 3,145,728
    const int n1 = B * A * S1;   //   393,216

    float* nll0 = (float*)d_ws;
    float* nll1 = nll0 + n0;

    hipMemsetAsync(out, 0, 4 * sizeof(float), stream);

    const int BS = 256;
    nll_neg_kernel<<<(n0 + BS - 1) / BS, BS, 0, stream>>>(logit0, nll0, B, A, S0);
    nll_neg_kernel<<<(n1 + BS - 1) / BS, BS, 0, stream>>>(logit1, nll1, B, A, S1);

    neg_loss_kernel<<<(n0 + BS - 1) / BS, BS, 0, stream>>>(nll0, prob_gt0, out, B, A, D0, H0, W0);
    neg_loss_kernel<<<(n1 + BS - 1) / BS, BS, 0, stream>>>(nll1, prob_gt1, out, B, A, D1, H1, W1);

    pos_loss_kernel<<<(B * P + BS - 1) / BS, BS, 0, stream>>>(logit0, prob_gt0, coord0, wcls, out, B, A, D0, H0, W0, P);
    pos_loss_kernel<<<(B * P + BS - 1) / BS, BS, 0, stream>>>(logit1, prob_gt1, coord1, wcls, out, B, A, D1, H1, W1, P);
}

// Round 2
// 157.894 us; speedup vs baseline: 3.0397x; 3.0397x over previous
//
#include <hip/hip_runtime.h>
#include <math.h>

#define NCLS 3

// ---------------------------------------------------------------------------
// Fused negative focal loss: per-block tile (TD x TH x TW), threads cover the
// (h,w) plane (TH*TW == blockDim.x). Stream planes along d:
//   - compute nll_neg halo plane ((TH+2)x(TW+2)) from logits into LDS
//   - per-thread 3x3 max from LDS  -> hwmax(plane) in a register
//   - 3-deep register sliding window over d -> full 3x3x3 NMS max
//   - compare, focal-weight, block-reduce, 2 atomics per block
// Requires W == TW, H % TH == 0, D % TD == 0.
// ---------------------------------------------------------------------------
template<int TD, int TH, int TW>
__global__ __launch_bounds__(TH * TW)
void fused_neg_kernel(const float* __restrict__ logit,
                      const float* __restrict__ prob_gt,
                      float* __restrict__ out,
                      int B, int A, int D, int H, int W) {
    constexpr int NT = TH * TW;
    constexpr int PH = TH + 2, PW = TW + 2, PLANE = PH * PW;
    __shared__ float nlp[2][PLANE];

    const int S = D * H * W;
    const int tilesH = H / TH;
    const int tilesD = D / TD;

    int bid = blockIdx.x;
    const int ht = bid % tilesH; bid /= tilesH;
    const int dt = bid % tilesD; bid /= tilesD;
    const int ba = bid;                  // b*A + a
    const int a = ba % A, b = ba / A;

    const int d0 = dt * TD, h0 = ht * TH;
    const float* lbase = logit + ((long)b * NCLS * A + a) * S;   // class-0 plane
    const long cstride = (long)A * S;
    const float* pg = prob_gt + (long)ba * S;

    const int tid = threadIdx.x;
    const int w = tid % TW, h = tid / TW;

    float hw0 = -INFINITY, hw1 = -INFINITY, c1 = 0.f;
    float loss = 0.f, cnt = 0.f;

    for (int step = -1; step <= TD; ++step) {
        float* buf = nlp[(step + 1) & 1];
        const int d = d0 + step;
        if (d >= 0 && d < D) {
            const float* lp = lbase + (long)d * H * W;
            #pragma unroll
            for (int e = 0; e < PLANE; e += NT) {
                int ee = e + tid;
                if (PLANE % NT != 0 && ee >= PLANE) break;
                int i = ee / PW, j = ee % PW;
                int hh = h0 - 1 + i, ww = j - 1;
                float v;
                if (hh >= 0 && hh < H && ww >= 0 && ww < W) {
                    long off = (long)hh * W + ww;
                    float l0 = lp[off];
                    float l1 = lp[off + cstride];
                    float l2 = lp[off + 2 * cstride];
                    float m = fmaxf(l0, fmaxf(l1, l2));
                    float e0 = __expf(l0 - m);
                    float e1 = __expf(l1 - m);
                    float e2 = __expf(l2 - m);
                    v = __logf(e0 + e1 + e2) - (l0 - m);
                } else {
                    v = -INFINITY;
                }
                buf[ee] = v;
            }
        } else {
            #pragma unroll
            for (int e = 0; e < PLANE; e += NT) {
                int ee = e + tid;
                if (PLANE % NT != 0 && ee >= PLANE) break;
                buf[ee] = -INFINITY;
            }
        }
        __syncthreads();

        // 3x3 max centered at (h+1, w+1) of the halo plane
        const float* r0 = buf + h * PW + w;
        const float* r1 = r0 + PW;
        const float* r2 = r1 + PW;
        float m0 = fmaxf(fmaxf(r0[0], r0[1]), r0[2]);
        float m1 = fmaxf(fmaxf(r1[0], r1[1]), r1[2]);
        float m2 = fmaxf(fmaxf(r2[0], r2[1]), r2[2]);
        float hw2 = fmaxf(m0, fmaxf(m1, m2));
        float cc = r1[1];   // center nll of this plane

        if (step >= 1) {
            const int dprev = d0 + step - 1;
            float pgv = pg[((long)dprev * H + (h0 + h)) * W + w];
            if (pgv == -1.0f) {
                float mp = fmaxf(hw0, fmaxf(hw1, hw2));
                if (mp == c1) {
                    float pn = __expf(-c1);
                    float wn = (1.f - pn) * (1.f - pn);
                    loss += c1 * wn;
                    cnt  += wn;
                }
            }
        }
        hw0 = hw1; hw1 = hw2; c1 = cc;
    }

    // wave (64-lane) reduce, then cross-wave via LDS, one atomic pair per block
    for (int off = 32; off > 0; off >>= 1) {
        loss += __shfl_down(loss, off);
        cnt  += __shfl_down(cnt, off);
    }
    __shared__ float sl[NT / 64], sc[NT / 64];
    int wave = tid >> 6;
    int lane = tid & 63;
    if (lane == 0) { sl[wave] = loss; sc[wave] = cnt; }
    __syncthreads();
    if (tid == 0) {
        float L = 0.f, C = 0.f;
        #pragma unroll
        for (int i = 0; i < NT / 64; ++i) { L += sl[i]; C += sc[i]; }
        atomicAdd(&out[1], L);
        atomicAdd(&out[3], C);
    }
}

// ---------------------------------------------------------------------------
// Positive gathers. out[0] += nll_t*w_pos, out[2] += w_pos.
// ---------------------------------------------------------------------------
__global__ void pos_loss_kernel(const float* __restrict__ logit,
                                const float* __restrict__ prob_gt,
                                const int* __restrict__ coord,
                                const float* __restrict__ wcls,
                                float* __restrict__ out,
                                int B, int A, int D, int H, int W, int P) {
    int i = blockIdx.x * blockDim.x + threadIdx.x;
    if (i >= B * P) return;
    int b = i / P;
    const int* c = coord + (long)i * 4;
    int a = c[0];
    float loss = 0.f, cnt = 0.f;
    if (a > -1) {
        int d = c[1], h = c[2], w = c[3];
        int S = D * H * W;
        int s = (d * H + h) * W + w;
        int cls = (int)prob_gt[((long)b * A + a) * S + s];
        const float* lp = logit + ((long)b * NCLS * A + a) * S + s;
        float l0 = lp[0];
        float l1 = lp[(long)A * S];
        float l2 = lp[2L * A * S];
        float m = fmaxf(l0, fmaxf(l1, l2));
        float e0 = __expf(l0 - m);
        float e1 = __expf(l1 - m);
        float e2 = __expf(l2 - m);
        float lsum = __logf(e0 + e1 + e2);
        float lc = (cls == 0) ? l0 : ((cls == 1) ? l1 : l2);
        float lpc = (lc - m) - lsum;
        float pt = __expf(lpc);
        float wp = (1.f - pt) * (1.f - pt) * wcls[cls];
        loss = (-lpc) * wp;
        cnt = wp;
    }
    atomicAdd(&out[0], loss);
    atomicAdd(&out[2], cnt);
}

extern "C" void kernel_launch(void* const* d_in, const int* in_sizes, int n_in,
                              void* d_out, int out_size, void* d_ws, size_t ws_size,
                              hipStream_t stream) {
    const float* logit0   = (const float*)d_in[0];
    const float* logit1   = (const float*)d_in[1];
    const float* prob_gt0 = (const float*)d_in[2];
    const float* prob_gt1 = (const float*)d_in[3];
    const int*   coord0   = (const int*)d_in[4];
    const int*   coord1   = (const int*)d_in[5];
    const float* wcls     = (const float*)d_in[6];
    float* out = (float*)d_out;

    const int B = 4, A = 3, P = 128;
    const int D0 = 64, H0 = 64, W0 = 64;
    const int D1 = 32, H1 = 32, W1 = 32;

    hipMemsetAsync(out, 0, 4 * sizeof(float), stream);

    // Level 0: tile 16x4x64 -> 12 * 4 * 16 = 768 blocks of 256 threads
    fused_neg_kernel<16, 4, 64><<<768, 256, 0, stream>>>(
        logit0, prob_gt0, out, B, A, D0, H0, W0);
    // Level 1: tile 8x8x32 -> 12 * 4 * 4 = 192 blocks of 256 threads
    fused_neg_kernel<8, 8, 32><<<192, 256, 0, stream>>>(
        logit1, prob_gt1, out, B, A, D1, H1, W1);

    const int BS = 256;
    pos_loss_kernel<<<(B * P + BS - 1) / BS, BS, 0, stream>>>(
        logit0, prob_gt0, coord0, wcls, out, B, A, D0, H0, W0, P);
    pos_loss_kernel<<<(B * P + BS - 1) / BS, BS, 0, stream>>>(
        logit1, prob_gt1, coord1, wcls, out, B, A, D1, H1, W1, P);
}